// Round 8
// baseline (402.823 us; speedup 1.0000x reference)
//
#include <hip/hip_runtime.h>

#define EPS 1e-6f
#define NCHUNK 32    // row chunks; rows/chunk = N/NCHUNK = 4096
#define WSLICE 16    // columns per slice
#define NSLICE 16    // D / WSLICE
#define LSTRIDE 17   // padded LDS row stride (floats) — randomizes banks
#define DEPTH 8      // software-pipeline depth (load groups in flight/wave)

// ws layout (4-byte elems):
//   [0]      int   counts[C]
//   [C]      float loss_acc
//   [C+1]    float npres_acc
//   [C+2]    int   done
//   [C+3]    float partials[C * NCHUNK*NSLICE * WSLICE]  (~33 MB, class-major,
//            each (chunk,slice) contribution = aligned 64 B block)
// memset zeroes the first C+3 elems only.

__global__ void hist_kernel(const int* __restrict__ lbls,
                            int* __restrict__ counts, int n) {
    int i = blockIdx.x * blockDim.x + threadIdx.x;
    if (i < n) atomicAdd(&counts[lbls[i]], 1);
}

// 512 blocks = 32 chunks x 16 slices. Sequential streaming read of feats with
// an explicit depth-8 register pipeline; scatter into LDS class table.
__global__ __launch_bounds__(256)
void stream_kernel(const float* __restrict__ feats,
                   const int* __restrict__ lbls,
                   float* __restrict__ partials,
                   int n, int c, int d) {
    extern __shared__ float lsum[];   // c * LSTRIDE floats = 68 KB
    int bid  = blockIdx.x;
    int s    = bid & (NSLICE - 1);    // column slice
    int k    = bid >> 4;              // row chunk
    int t    = threadIdx.x;
    int w    = t >> 6;                // wave 0..3
    int lane = t & 63;
    int rsub = lane >> 2;             // 0..15: row within a 16-row group
    int a    = lane & 3;              // which float4 of the 64 B slice

    for (int i = t; i < c * LSTRIDE; i += 256) lsum[i] = 0.0f;
    __syncthreads();

    int rows    = n / NCHUNK;         // 4096
    int row0    = k * rows;
    int ngroups = rows / 64;          // 64 groups of 16 rows per wave
    const float4* f4 = (const float4*)feats;
    int stride4 = d >> 2;             // 64
    int colbase = s * 4 + a;          // float4 index within the row

    float4 v[DEPTH];
    int    lb[DEPTH];

#pragma unroll
    for (int p = 0; p < DEPTH; ++p) {
        int r = row0 + (p * 4 + w) * 16 + rsub;
        lb[p] = lbls[r];
        v[p]  = f4[(size_t)r * stride4 + colbase];
    }

    for (int base = 0; base < ngroups; base += DEPTH) {
#pragma unroll
        for (int p = 0; p < DEPTH; ++p) {
            float4 val = v[p];
            int    l   = lb[p];
            int nj = base + DEPTH + p;
            if (nj < ngroups) {               // refill slot p (group nj)
                int r = row0 + (nj * 4 + w) * 16 + rsub;
                lb[p] = lbls[r];
                v[p]  = f4[(size_t)r * stride4 + colbase];
            }
            float* dst = &lsum[l * LSTRIDE + a * 4];
            unsafeAtomicAdd(dst + 0, val.x);
            unsafeAtomicAdd(dst + 1, val.y);
            unsafeAtomicAdd(dst + 2, val.z);
            unsafeAtomicAdd(dst + 3, val.w);
        }
    }
    __syncthreads();

    // flush: class cc's 16-float contribution is an aligned 64 B block at
    // partials[cc*(NCHUNK*NSLICE*16) + (k*NSLICE+s)*16 + col]
    int chunk = k * NSLICE + s;
    int per_class = NCHUNK * NSLICE * WSLICE;   // 8192
    for (int i = t; i < c * WSLICE; i += 256) {
        int cc = i >> 4, col = i & 15;
        partials[(size_t)cc * per_class + chunk * WSLICE + col]
            = lsum[cc * LSTRIDE + col];
    }
}

// one block per class: fully-coalesced reduce of the class's 8 KB partial
// block (32 chunks x 256 cols), mean + Mahalanobis, last-done writes scalar.
__global__ __launch_bounds__(256)
void finalize_kernel(const float* __restrict__ partials,
                     const int* __restrict__ counts,
                     const float* __restrict__ proto,
                     const float* __restrict__ cov,
                     float* __restrict__ loss_acc,
                     float* __restrict__ npres_acc,
                     int* __restrict__ done,
                     float* __restrict__ out, int c_total, int d) {
    int cc = blockIdx.x;
    int t  = threadIdx.x;               // global column (s = t>>4, col = t&15)
    const float* base = partials + (size_t)cc * (NCHUNK * NSLICE * WSLICE);

    float a = 0.0f;
#pragma unroll 8
    for (int kk = 0; kk < NCHUNK; ++kk)
        a += base[kk * 256 + t];        // (k*16+s)*16 + col == k*256 + t

    int cnt = counts[cc];
    float present = (cnt > 0) ? 1.0f : 0.0f;
    float mean = a / fmaxf((float)cnt, 1.0f);
    size_t idx = (size_t)cc * d + t;
    float diff = mean - proto[idx];
    float pe = present * diff * diff / (cov[idx] + EPS);

    for (int off = 32; off > 0; off >>= 1)
        pe += __shfl_down(pe, off, 64);
    __shared__ float sred[4];
    if ((t & 63) == 0) sred[t >> 6] = pe;
    __syncthreads();
    if (t == 0) {
        atomicAdd(loss_acc, (sred[0] + sred[1]) + (sred[2] + sred[3]));
        atomicAdd(npres_acc, present);
        __threadfence();
        int prev = atomicAdd(done, 1);
        if (prev == c_total - 1) {
            float L = atomicAdd(loss_acc, 0.0f);   // coherent read
            float P = atomicAdd(npres_acc, 0.0f);
            out[0] = L / (P * (float)d);
        }
    }
}

extern "C" void kernel_launch(void* const* d_in, const int* in_sizes, int n_in,
                              void* d_out, int out_size, void* d_ws, size_t ws_size,
                              hipStream_t stream) {
    const float* feats = (const float*)d_in[0];
    const int*   lbls  = (const int*)d_in[1];
    const float* proto = (const float*)d_in[2];
    const float* cov   = (const float*)d_in[3];

    int n_rows = in_sizes[1];              // N = 131072
    int d      = in_sizes[0] / n_rows;     // D = 256
    int c      = in_sizes[2] / d;          // C = 1000

    int*   counts    = (int*)d_ws;
    float* loss_acc  = (float*)d_ws + c;
    float* npres_acc = loss_acc + 1;
    int*   done      = (int*)d_ws + c + 2;
    float* partials  = (float*)d_ws + c + 3;

    hipMemsetAsync(d_ws, 0, ((size_t)c + 3) * sizeof(int), stream);

    int nb = (n_rows + 255) / 256;
    hist_kernel<<<nb, 256, 0, stream>>>(lbls, counts, n_rows);

    size_t lds_bytes = (size_t)c * LSTRIDE * sizeof(float);   // 68 KB
    stream_kernel<<<NCHUNK * NSLICE, 256, lds_bytes, stream>>>(
        feats, lbls, partials, n_rows, c, d);

    finalize_kernel<<<c, 256, 0, stream>>>(partials, counts, proto, cov,
                                           loss_acc, npres_acc, done,
                                           (float*)d_out, c, d);
}

// Round 9
// 373.591 us; speedup vs baseline: 1.0782x; 1.0782x over previous
//
#include <hip/hip_runtime.h>

#define EPS 1e-6f
#define NCHUNK 32     // row chunks (4096 rows = 4 MB window each)
#define NSLICE 8      // column slices per row
#define SLICEW 32     // columns per slice (128 B segments)
#define LSTRIDE 33    // LDS table row stride: 32 cols + 1 count slot

// ws layout (4-byte elems):
//   [0] float loss_acc   [1] float npres_acc   [2] int done
//   [3]                 float pcnt[NCHUNK*C]
//   [3+NCHUNK*C]        float partials[NCHUNK*NSLICE*C*SLICEW]  (~33 MB)
// memset zeroes only the first 3 words; pcnt/partials fully overwritten.

__global__ __launch_bounds__(1024, 4)
void stream_kernel(const float* __restrict__ feats,
                   const int* __restrict__ lbls,
                   float* __restrict__ partials,
                   float* __restrict__ pcnt,
                   int n, int c, int d) {
    extern __shared__ float smem[];
    float* lsum = smem;                         // c * LSTRIDE floats (132 KB)
    int*   sLbl = (int*)(smem + (size_t)c * LSTRIDE);   // rows-per-chunk ints

    // XCD swizzle: bid%8 = XCD; put all 8 slices of a chunk on one XCD.
    int bid = blockIdx.x;
    int x = bid & 7;
    int m = bid >> 3;
    int s = m & 7;                              // slice 0..7
    int k = ((m >> 3) << 3) | x;                // chunk 0..31, k%8 == XCD

    int tid  = threadIdx.x;
    int w    = tid >> 6;                        // wave 0..15
    int lane = tid & 63;
    int rsub = lane >> 3;                       // 0..7 row within 8-row group
    int a    = lane & 7;                        // float4 within 32-col slice

    int rows = n / NCHUNK;                      // 4096
    int row0 = k * rows;

    for (int i = tid; i < c * LSTRIDE; i += 1024) lsum[i] = 0.0f;
    for (int i = tid; i < rows; i += 1024)        sLbl[i] = lbls[row0 + i];
    __syncthreads();

    const float4* f4 = (const float4*)feats;
    int stride4 = d >> 2;                       // 64
    int colbase = s * 8 + a;                    // float4 index within the row

    // wave w owns a contiguous 256-row span; 32 iterations of 8 rows.
    int wrow0 = w * (rows >> 4);
    int iters = rows >> 7;                      // 32
    bool docnt = (s == 0) && (a == 0);

    // depth-2 register pipeline (branch-free refill)
    int r0 = row0 + wrow0 + rsub;
    float4 vnext = f4[(size_t)r0 * stride4 + colbase];
    for (int it = 0; it < iters; ++it) {
        float4 v = vnext;
        int nit = (it + 1 < iters) ? it + 1 : it;
        int rn = row0 + wrow0 + nit * 8 + rsub;
        vnext = f4[(size_t)rn * stride4 + colbase];

        int l = sLbl[wrow0 + it * 8 + rsub];
        float* dst = &lsum[l * LSTRIDE + a * 4];
        unsafeAtomicAdd(dst + 0, v.x);
        unsafeAtomicAdd(dst + 1, v.y);
        unsafeAtomicAdd(dst + 2, v.z);
        unsafeAtomicAdd(dst + 3, v.w);
        if (docnt) unsafeAtomicAdd(&lsum[l * LSTRIDE + SLICEW], 1.0f);
    }
    __syncthreads();

    // fully-sequential flush: 128 KB per block
    float* dstp = partials + (size_t)(k * NSLICE + s) * c * SLICEW;
    for (int i = tid; i < c * SLICEW; i += 1024)
        dstp[i] = lsum[(i >> 5) * LSTRIDE + (i & 31)];
    if (s == 0)
        for (int i = tid; i < c; i += 1024)
            pcnt[(size_t)k * c + i] = lsum[i * LSTRIDE + SLICEW];
}

// one block per class: reduce 32 chunk-partials, mean + Mahalanobis,
// last-done block computes the final scalar.
__global__ __launch_bounds__(256)
void finalize_kernel(const float* __restrict__ partials,
                     const float* __restrict__ pcnt,
                     const float* __restrict__ proto,
                     const float* __restrict__ cov,
                     float* __restrict__ loss_acc,
                     float* __restrict__ npres_acc,
                     int* __restrict__ done,
                     float* __restrict__ out, int c_total, int d) {
    int cc = blockIdx.x;
    int t  = threadIdx.x;
    int sg = t >> 5, col = t & 31;              // slice group, col within

    float a = 0.0f;
#pragma unroll 8
    for (int k = 0; k < NCHUNK; ++k)
        a += partials[((size_t)(k * NSLICE + sg) * c_total + cc) * SLICEW + col];

    __shared__ float scnt;
    {
        float v = (t < NCHUNK) ? pcnt[(size_t)t * c_total + cc] : 0.0f;
        if (t < 64) {
            for (int off = 32; off > 0; off >>= 1) v += __shfl_down(v, off, 64);
            if (t == 0) scnt = v;
        }
    }
    __syncthreads();
    float cnt = scnt;

    float present = (cnt > 0.0f) ? 1.0f : 0.0f;
    float mean = a / fmaxf(cnt, 1.0f);
    size_t idx = (size_t)cc * d + t;
    float diff = mean - proto[idx];
    float pe = present * diff * diff / (cov[idx] + EPS);

    for (int off = 32; off > 0; off >>= 1)
        pe += __shfl_down(pe, off, 64);
    __shared__ float sred[4];
    if ((t & 63) == 0) sred[t >> 6] = pe;
    __syncthreads();
    if (t == 0) {
        atomicAdd(loss_acc, (sred[0] + sred[1]) + (sred[2] + sred[3]));
        atomicAdd(npres_acc, present);
        __threadfence();
        int prev = atomicAdd(done, 1);
        if (prev == c_total - 1) {
            float L = atomicAdd(loss_acc, 0.0f);   // coherent read
            float P = atomicAdd(npres_acc, 0.0f);
            out[0] = L / (P * (float)d);
        }
    }
}

extern "C" void kernel_launch(void* const* d_in, const int* in_sizes, int n_in,
                              void* d_out, int out_size, void* d_ws, size_t ws_size,
                              hipStream_t stream) {
    const float* feats = (const float*)d_in[0];
    const int*   lbls  = (const int*)d_in[1];
    const float* proto = (const float*)d_in[2];
    const float* cov   = (const float*)d_in[3];

    int n_rows = in_sizes[1];              // N = 131072
    int d      = in_sizes[0] / n_rows;     // D = 256
    int c      = in_sizes[2] / d;          // C = 1000

    float* loss_acc  = (float*)d_ws;
    float* npres_acc = loss_acc + 1;
    int*   done      = (int*)d_ws + 2;
    float* pcnt      = (float*)d_ws + 3;
    float* partials  = pcnt + (size_t)NCHUNK * c;

    hipMemsetAsync(d_ws, 0, 3 * sizeof(int), stream);

    size_t lds_bytes = (size_t)c * LSTRIDE * sizeof(float)
                     + (size_t)(n_rows / NCHUNK) * sizeof(int);   // ~148 KB
    hipFuncSetAttribute((const void*)stream_kernel,
                        hipFuncAttributeMaxDynamicSharedMemorySize,
                        (int)lds_bytes);

    stream_kernel<<<NCHUNK * NSLICE, 1024, lds_bytes, stream>>>(
        feats, lbls, partials, pcnt, n_rows, c, d);

    finalize_kernel<<<c, 256, 0, stream>>>(partials, pcnt, proto, cov,
                                           loss_acc, npres_acc, done,
                                           (float*)d_out, c, d);
}